// Round 2
// baseline (51667.224 us; speedup 1.0000x reference)
//
#include <hip/hip_runtime.h>
#include <hip/hip_bf16.h>
#include <stdint.h>

// Problem constants
#define T_STEPS 256
#define BATCH   32
#define HID     1024
#define KDIM    2048   // input width of every layer (D_IN = 2H = 2048)
#define NDIM    6144   // 2 dirs * 3H
#define MDIM    8192   // T*B

typedef __attribute__((ext_vector_type(8))) short bfrag;   // 8 bf16 = 4 VGPRs
typedef __attribute__((ext_vector_type(4))) float ffrag;   // 4 f32 accum

__device__ inline unsigned short f2bf(float f) {
  __hip_bfloat16 h = __float2bfloat16(f);
  unsigned short u;
  __builtin_memcpy(&u, &h, 2);
  return u;
}

__device__ inline void gld_lds16(const void* g, void* l) {
  // async global->LDS, 16B per lane; LDS dest = wave-uniform base + lane*16
  __builtin_amdgcn_global_load_lds(
      (const __attribute__((address_space(1))) void*)g,
      (__attribute__((address_space(3))) void*)l,
      16, 0, 0);
}

// ---------------------------------------------------------------- converts
__global__ __launch_bounds__(256) void f32_to_bf16_k(
    const float* __restrict__ src, unsigned short* __restrict__ dst, int n4) {
  int i = blockIdx.x * 256 + threadIdx.x;
  if (i >= n4) return;
  float4 v = ((const float4*)src)[i];
  ushort4 o;
  o.x = f2bf(v.x); o.y = f2bf(v.y); o.z = f2bf(v.z); o.w = f2bf(v.w);
  ((ushort4*)dst)[i] = o;
}

// ---------------------------------------------------------------- GEMM
// C[m][n] = sum_k A[m][k] * Bw[n][k] + bias[n]
// A: (8192, 2048) bf16 row-major; Bw: (6144, 2048) bf16 row-major; C f32.
// 128x128 block tile, 4 waves each 64x64, BK=32, global_load_lds width 16.
__global__ __launch_bounds__(256) void gemm_xp(
    const unsigned short* __restrict__ A,
    const unsigned short* __restrict__ Bw,
    const float* __restrict__ bias,
    float* __restrict__ C) {
  __shared__ __align__(16) unsigned short Asl[128 * 32];
  __shared__ __align__(16) unsigned short Bsl[128 * 32];
  const int tid  = threadIdx.x;
  const int wave = tid >> 6;
  const int lane = tid & 63;
  const int quad = lane >> 4;
  const int lm   = lane & 15;
  const int m0 = blockIdx.x * 128;
  const int n0 = blockIdx.y * 128;
  const int wm = (wave & 1) * 64;
  const int wn = (wave >> 1) * 64;

  ffrag acc[4][4];
#pragma unroll
  for (int a = 0; a < 4; a++)
#pragma unroll
    for (int b = 0; b < 4; b++) {
      ffrag z = {0.0f, 0.0f, 0.0f, 0.0f};
      acc[a][b] = z;
    }

  // staging assignment: thread t loads row r = t>>2, 16B chunk c = t&3
  const int r = tid >> 2;
  const int c = tid & 3;
  const unsigned short* Ag0 = A  + (size_t)(m0 + r) * KDIM + c * 8;
  const unsigned short* Ag1 = Ag0 + (size_t)64 * KDIM;
  const unsigned short* Bg0 = Bw + (size_t)(n0 + r) * KDIM + c * 8;
  const unsigned short* Bg1 = Bg0 + (size_t)64 * KDIM;
  char* Al = (char*)Asl + wave * 1024;   // wave-uniform LDS base
  char* Bl = (char*)Bsl + wave * 1024;

  for (int kk = 0; kk < KDIM; kk += 32) {
    __syncthreads();               // prev compute done before overwrite
    gld_lds16(Ag0 + kk, Al);
    gld_lds16(Ag1 + kk, Al + 4096);
    gld_lds16(Bg0 + kk, Bl);
    gld_lds16(Bg1 + kk, Bl + 4096);
    __syncthreads();               // drains vmcnt, loads visible

    bfrag af[4], bf[4];
#pragma unroll
    for (int mt = 0; mt < 4; mt++)
      af[mt] = *(const bfrag*)((const char*)Asl + (wm + mt * 16 + lm) * 64 + quad * 16);
#pragma unroll
    for (int nt = 0; nt < 4; nt++)
      bf[nt] = *(const bfrag*)((const char*)Bsl + (wn + nt * 16 + lm) * 64 + quad * 16);
#pragma unroll
    for (int mt = 0; mt < 4; mt++)
#pragma unroll
      for (int nt = 0; nt < 4; nt++)
        acc[mt][nt] = __builtin_amdgcn_mfma_f32_16x16x32_bf16(
            af[mt], bf[nt], acc[mt][nt], 0, 0, 0);
  }

  // epilogue: C/D layout col=lane&15, row=quad*4+i
#pragma unroll
  for (int mt = 0; mt < 4; mt++) {
#pragma unroll
    for (int nt = 0; nt < 4; nt++) {
      int mrow = m0 + wm + mt * 16 + quad * 4;
      int ncol = n0 + wn + nt * 16 + lm;
      float bi = bias[ncol];
#pragma unroll
      for (int i = 0; i < 4; i++)
        C[(size_t)(mrow + i) * NDIM + ncol] = acc[mt][nt][i] + bi;
    }
  }
}

// ---------------------------------------------------------------- GRU step
// One launch per time step, both directions in the grid.
// grid: 256 blocks (d = blk>>7, jb = blk&127), 256 threads (b = tid&31, j-slice = tid>>5)
// Writes bf16 to out_bf (intermediate layers) OR fp32 to out_f32 (final layer).
__global__ __launch_bounds__(256) void gru_step(
    const float* __restrict__ xp,    // (T*B, 6144) this layer, bias_ih included
    const float* __restrict__ Whh,   // (2, 3072, 1024) this layer
    const float* __restrict__ bhh,   // (2, 3072) this layer
    const float* __restrict__ h_in,  // (2, 32, 1024)
    float* __restrict__ h_out,       // (2, 32, 1024)
    unsigned short* __restrict__ out_bf, // (T, B, 2048) bf16, or null
    float* __restrict__ out_f32,         // (T, B, 2048) f32,  or null
    int s) {
  const int blk = blockIdx.x;
  const int d  = blk >> 7;
  const int jb = blk & 127;
  const int tid = threadIdx.x;
  const int b = tid & 31;
  const int j = jb * 8 + (tid >> 5);
  const int t = d ? (T_STEPS - 1 - s) : s;

  const float* hrow = h_in + (d * BATCH + b) * HID;
  const float* Wr = Whh + ((size_t)d * 3072 + j) * HID;
  const float* Wz = Wr + (size_t)1024 * HID;
  const float* Wn = Wz + (size_t)1024 * HID;

  float ar = 0.f, az = 0.f, an = 0.f;
#pragma unroll 4
  for (int k = 0; k < HID; k += 4) {
    float4 h4 = *(const float4*)(hrow + k);
    float4 w;
    w = *(const float4*)(Wr + k);
    ar += h4.x * w.x + h4.y * w.y + h4.z * w.z + h4.w * w.w;
    w = *(const float4*)(Wz + k);
    az += h4.x * w.x + h4.y * w.y + h4.z * w.z + h4.w * w.w;
    w = *(const float4*)(Wn + k);
    an += h4.x * w.x + h4.y * w.y + h4.z * w.z + h4.w * w.w;
  }
  ar += bhh[d * 3072 + j];
  az += bhh[d * 3072 + 1024 + j];
  an += bhh[d * 3072 + 2048 + j];

  const float* xrow = xp + ((size_t)t * BATCH + b) * NDIM + d * 3072;
  float xr = xrow[j], xz = xrow[1024 + j], xn = xrow[2048 + j];

  float rr = 1.0f / (1.0f + __expf(-(xr + ar)));
  float zz = 1.0f / (1.0f + __expf(-(xz + az)));
  float nn = tanhf(xn + rr * an);
  float hp = hrow[j];
  float hv = (1.0f - zz) * nn + zz * hp;

  h_out[(d * BATCH + b) * HID + j] = hv;
  const size_t oidx = ((size_t)t * BATCH + b) * 2048 + d * HID + j;
  if (out_bf) out_bf[oidx] = f2bf(hv);
  else        out_f32[oidx] = hv;
}

// ---------------------------------------------------------------- launch
extern "C" void kernel_launch(void* const* d_in, const int* in_sizes, int n_in,
                              void* d_out, int out_size, void* d_ws, size_t ws_size,
                              hipStream_t stream) {
  const float* x    = (const float*)d_in[0];  // (256,32,2048)
  const float* h0   = (const float*)d_in[1];  // (6,32,1024)
  const float* W_ih = (const float*)d_in[2];  // (3,2,3072,2048)
  const float* W_hh = (const float*)d_in[3];  // (3,2,3072,1024)
  const float* b_ih = (const float*)d_in[4];  // (3,2,3072)
  const float* b_hh = (const float*)d_in[5];  // (3,2,3072)
  float* out = (float*)d_out;                 // (256,32,2048) float32 (ref output dtype)

  // workspace carve (total ~248.5 MiB)
  char* w = (char*)d_ws;
  float* xp = (float*)w;                 w += (size_t)MDIM * NDIM * 4;        // 201.3 MB
  unsigned short* act = (unsigned short*)w; w += (size_t)MDIM * KDIM * 2;     // 33.6 MB
  unsigned short* Wb  = (unsigned short*)w; w += (size_t)2 * 3072 * KDIM * 2; // 25.2 MB
  float* ha = (float*)w;                 w += 2 * BATCH * HID * 4;
  float* hb = (float*)w;                 w += 2 * BATCH * HID * 4;

  // x -> bf16 (layer-0 GEMM A operand)
  f32_to_bf16_k<<<16384, 256, 0, stream>>>(x, act, MDIM * KDIM / 4);

  for (int l = 0; l < 3; l++) {
    // W_ih[l] -> bf16
    f32_to_bf16_k<<<12288, 256, 0, stream>>>(W_ih + (size_t)l * 2 * 3072 * KDIM,
                                             Wb, 2 * 3072 * KDIM / 4);
    // xp = act * W_ih^T + b_ih
    dim3 g(MDIM / 128, NDIM / 128);
    gemm_xp<<<g, 256, 0, stream>>>(act, Wb, b_ih + l * NDIM, xp);

    unsigned short* dst_bf = (l == 2) ? nullptr : act;
    float* dst_f32 = (l == 2) ? out : nullptr;
    const float* Whl = W_hh + (size_t)l * 2 * 3072 * HID;
    const float* bhl = b_hh + l * NDIM;
    const float* h0l = h0 + (size_t)l * 2 * BATCH * HID;

    for (int s = 0; s < T_STEPS; s++) {
      const float* hin = (s == 0) ? h0l : ((s & 1) ? ha : hb);
      float* hout = (s & 1) ? hb : ha;
      gru_step<<<256, 256, 0, stream>>>(xp, Whl, bhl, hin, hout, dst_bf, dst_f32, s);
    }
  }
}

// Round 3
// 18721.223 us; speedup vs baseline: 2.7598x; 2.7598x over previous
//
#include <hip/hip_runtime.h>
#include <hip/hip_bf16.h>
#include <hip/hip_cooperative_groups.h>
#include <stdint.h>

namespace cg = cooperative_groups;

// Problem constants
#define T_STEPS 256
#define BATCH   32
#define HID     1024
#define KDIM    2048   // input width of every layer (D_IN = 2H = 2048)
#define NDIM    6144   // 2 dirs * 3H
#define MDIM    8192   // T*B

typedef __attribute__((ext_vector_type(8))) short bfrag;   // 8 bf16 = 4 VGPRs
typedef __attribute__((ext_vector_type(4))) float ffrag;   // 4 f32 accum

__device__ inline unsigned short f2bf(float f) {
  __hip_bfloat16 h = __float2bfloat16(f);
  unsigned short u;
  __builtin_memcpy(&u, &h, 2);
  return u;
}

__device__ inline void gld_lds16(const void* g, void* l) {
  __builtin_amdgcn_global_load_lds(
      (const __attribute__((address_space(1))) void*)g,
      (__attribute__((address_space(3))) void*)l,
      16, 0, 0);
}

// ---------------------------------------------------------------- converts
__global__ __launch_bounds__(256) void f32_to_bf16_k(
    const float* __restrict__ src, unsigned short* __restrict__ dst, int n4) {
  int i = blockIdx.x * 256 + threadIdx.x;
  if (i >= n4) return;
  float4 v = ((const float4*)src)[i];
  ushort4 o;
  o.x = f2bf(v.x); o.y = f2bf(v.y); o.z = f2bf(v.z); o.w = f2bf(v.w);
  ((ushort4*)dst)[i] = o;
}

// ---------------------------------------------------------------- GEMM (xp)
// C[m][n] = sum_k A[m][k] * Bw[n][k] + bias[n]
// A: (8192,2048) bf16 rm; Bw: (6144,2048) bf16 rm; C f32.
__global__ __launch_bounds__(256) void gemm_xp(
    const unsigned short* __restrict__ A,
    const unsigned short* __restrict__ Bw,
    const float* __restrict__ bias,
    float* __restrict__ C) {
  __shared__ __align__(16) unsigned short Asl[128 * 32];
  __shared__ __align__(16) unsigned short Bsl[128 * 32];
  const int tid  = threadIdx.x;
  const int wave = tid >> 6;
  const int lane = tid & 63;
  const int quad = lane >> 4;
  const int lm   = lane & 15;
  const int m0 = blockIdx.x * 128;
  const int n0 = blockIdx.y * 128;
  const int wm = (wave & 1) * 64;
  const int wn = (wave >> 1) * 64;

  ffrag acc[4][4];
#pragma unroll
  for (int a = 0; a < 4; a++)
#pragma unroll
    for (int b = 0; b < 4; b++) {
      ffrag z = {0.0f, 0.0f, 0.0f, 0.0f};
      acc[a][b] = z;
    }

  const int r = tid >> 2;
  const int c = tid & 3;
  const unsigned short* Ag0 = A  + (size_t)(m0 + r) * KDIM + c * 8;
  const unsigned short* Ag1 = Ag0 + (size_t)64 * KDIM;
  const unsigned short* Bg0 = Bw + (size_t)(n0 + r) * KDIM + c * 8;
  const unsigned short* Bg1 = Bg0 + (size_t)64 * KDIM;
  char* Al = (char*)Asl + wave * 1024;
  char* Bl = (char*)Bsl + wave * 1024;

  for (int kk = 0; kk < KDIM; kk += 32) {
    __syncthreads();
    gld_lds16(Ag0 + kk, Al);
    gld_lds16(Ag1 + kk, Al + 4096);
    gld_lds16(Bg0 + kk, Bl);
    gld_lds16(Bg1 + kk, Bl + 4096);
    __syncthreads();

    bfrag af[4], bf[4];
#pragma unroll
    for (int mt = 0; mt < 4; mt++)
      af[mt] = *(const bfrag*)((const char*)Asl + (wm + mt * 16 + lm) * 64 + quad * 16);
#pragma unroll
    for (int nt = 0; nt < 4; nt++)
      bf[nt] = *(const bfrag*)((const char*)Bsl + (wn + nt * 16 + lm) * 64 + quad * 16);
#pragma unroll
    for (int mt = 0; mt < 4; mt++)
#pragma unroll
      for (int nt = 0; nt < 4; nt++)
        acc[mt][nt] = __builtin_amdgcn_mfma_f32_16x16x32_bf16(
            af[mt], bf[nt], acc[mt][nt], 0, 0, 0);
  }

#pragma unroll
  for (int mt = 0; mt < 4; mt++) {
#pragma unroll
    for (int nt = 0; nt < 4; nt++) {
      int mrow = m0 + wm + mt * 16 + quad * 4;
      int ncol = n0 + wn + nt * 16 + lm;
      float bi = bias[ncol];
#pragma unroll
      for (int i = 0; i < 4; i++)
        C[(size_t)(mrow + i) * NDIM + ncol] = acc[mt][nt][i] + bi;
    }
  }
}

// ---------------------------------------------------------------- persistent scan
// One cooperative launch per layer; 256 steps inside, one grid.sync per step.
// grid 128: blk>>6 = dir, (blk&63)*16 = owned h-output base j0.
// 384 threads = 6 waves: wave = g*2+mt (g=gate 0..2, mt=b-half).
// Per wave per step: one 16x16 C tile via 32x mfma_16x16x32_bf16 over K=1024.
// A = h_prev bf16 (global, L2), B = W_hh bf16 (global, L2-resident 12.6MB).
__global__ __launch_bounds__(384, 1) void gru_scan(
    const float* __restrict__ xp,          // (T*B, 6144), bias_ih included
    const unsigned short* __restrict__ Wbf,// (2,3072,1024) bf16, this layer
    const float* __restrict__ bhh,         // (2,3072) this layer
    const float* __restrict__ h0,          // (2,32,1024) this layer
    float* __restrict__ hfA, float* __restrict__ hfB,
    unsigned short* __restrict__ hbA, unsigned short* __restrict__ hbB,
    unsigned short* __restrict__ out_bf,   // (T,B,2048) bf16 or null
    float* __restrict__ out_f32) {         // (T,B,2048) f32 (final layer)
  cg::grid_group grid = cg::this_grid();
  __shared__ float gbuf[3][32][17];        // [gate][b][j], +1 pad

  const int blk  = blockIdx.x;
  const int d    = blk >> 6;
  const int j0   = (blk & 63) * 16;
  const int tid  = threadIdx.x;
  const int wave = tid / 64;
  const int lane = tid & 63;
  const int quad = lane >> 4;
  const int lm   = lane & 15;
  const int g    = wave >> 1;              // gate
  const int mt   = wave & 1;               // b-half

  // init own slice of h buffers from h0 (fp32 + bf16 shadow)
  for (int o = tid; o < 512; o += 384) {
    int b = o >> 4, j = o & 15;
    float v = h0[(d * 32 + b) * HID + j0 + j];
    hfA[(d * 32 + b) * HID + j0 + j] = v;
    hbA[(d * 32 + b) * HID + j0 + j] = f2bf(v);
  }
  grid.sync();

  // fragment base pointers (A: m=lane&15 -> b row; k=quad*8.. ; B: n=lane&15 -> W row)
  const unsigned short* wrow =
      Wbf + ((size_t)(d * 3072 + g * 1024 + j0 + lm)) * HID + quad * 8;
  const int arow_off = (d * 32 + mt * 16 + lm) * HID + quad * 8;

  const float* hf_prev = hfA; float* hf_next = hfB;
  const unsigned short* hb_prev = hbA; unsigned short* hb_next = hbB;

  for (int s = 0; s < T_STEPS; s++) {
    const int t = d ? (T_STEPS - 1 - s) : s;

    // ---- MFMA phase: acc = h_prev x W_g^T for this wave's tile
    ffrag acc = {0.0f, 0.0f, 0.0f, 0.0f};
    const unsigned short* ap = hb_prev + arow_off;
    {
      bfrag a  = *(const bfrag*)(ap);
      bfrag bb = *(const bfrag*)(wrow);
#pragma unroll 4
      for (int k0 = 32; k0 < HID; k0 += 32) {
        bfrag a2 = *(const bfrag*)(ap + k0);
        bfrag b2 = *(const bfrag*)(wrow + k0);
        acc = __builtin_amdgcn_mfma_f32_16x16x32_bf16(a, bb, acc, 0, 0, 0);
        a = a2; bb = b2;
      }
      acc = __builtin_amdgcn_mfma_f32_16x16x32_bf16(a, bb, acc, 0, 0, 0);
    }

    __syncthreads();   // previous epilogue's gbuf reads complete
    // C/D layout: col(n)=lm -> j, row(m)=quad*4+i -> b (within half mt)
#pragma unroll
    for (int i = 0; i < 4; i++)
      gbuf[g][mt * 16 + quad * 4 + i][lm] = acc[i];
    __syncthreads();

    // ---- gate math + stores (512 outputs over 384 threads)
    for (int o = tid; o < 512; o += 384) {
      int b = o >> 4, j = o & 15;
      int jg = j0 + j;
      const float* xrow = xp + ((size_t)t * BATCH + b) * NDIM + d * 3072;
      float hr = gbuf[0][b][j] + bhh[d * 3072 + jg];
      float hz = gbuf[1][b][j] + bhh[d * 3072 + 1024 + jg];
      float hn = gbuf[2][b][j] + bhh[d * 3072 + 2048 + jg];
      float xr = xrow[jg], xz = xrow[1024 + jg], xn = xrow[2048 + jg];
      float rr = 1.0f / (1.0f + __expf(-(xr + hr)));
      float zz = 1.0f / (1.0f + __expf(-(xz + hz)));
      float nn = tanhf(xn + rr * hn);
      float hp = hf_prev[(d * 32 + b) * HID + jg];
      float hv = (1.0f - zz) * nn + zz * hp;
      hf_next[(d * 32 + b) * HID + jg] = hv;
      hb_next[(d * 32 + b) * HID + jg] = f2bf(hv);
      size_t oi = ((size_t)t * BATCH + b) * 2048 + d * HID + jg;
      if (out_bf) out_bf[oi] = f2bf(hv);
      else        out_f32[oi] = hv;
    }

    grid.sync();       // h_next visible device-wide before next step reads it

    const float* tf = hf_prev; hf_prev = hf_next; hf_next = (float*)tf;
    const unsigned short* tb = hb_prev; hb_prev = hb_next; hb_next = (unsigned short*)tb;
  }
}

// ---------------------------------------------------------------- launch
extern "C" void kernel_launch(void* const* d_in, const int* in_sizes, int n_in,
                              void* d_out, int out_size, void* d_ws, size_t ws_size,
                              hipStream_t stream) {
  const float* x    = (const float*)d_in[0];  // (256,32,2048)
  const float* h0   = (const float*)d_in[1];  // (6,32,1024)
  const float* W_ih = (const float*)d_in[2];  // (3,2,3072,2048)
  const float* W_hh = (const float*)d_in[3];  // (3,2,3072,1024)
  const float* b_ih = (const float*)d_in[4];  // (3,2,3072)
  const float* b_hh = (const float*)d_in[5];  // (3,2,3072)
  float* out = (float*)d_out;                 // (256,32,2048) f32

  // workspace carve (~248.8 MiB total; ws held >=248.4 MiB in round 2)
  char* w = (char*)d_ws;
  float* xp = (float*)w;                    w += (size_t)MDIM * NDIM * 4;     // 201.3 MB
  unsigned short* act = (unsigned short*)w; w += (size_t)MDIM * KDIM * 2;     // 33.6 MB
  unsigned short* Wub = (unsigned short*)w; w += (size_t)2 * 3072 * KDIM * 2; // 25.2 MB (union: W_ih-bf16 then W_hh-bf16)
  float* hfA = (float*)w;                   w += (size_t)2 * BATCH * HID * 4;
  float* hfB = (float*)w;                   w += (size_t)2 * BATCH * HID * 4;
  unsigned short* hbA = (unsigned short*)w; w += (size_t)2 * BATCH * HID * 2;
  unsigned short* hbB = (unsigned short*)w; w += (size_t)2 * BATCH * HID * 2;

  // x -> bf16 (layer-0 GEMM A operand)
  f32_to_bf16_k<<<16384, 256, 0, stream>>>(x, act, MDIM * KDIM / 4);

  for (int l = 0; l < 3; l++) {
    // W_ih[l] -> bf16 into union buffer
    f32_to_bf16_k<<<12288, 256, 0, stream>>>(
        W_ih + (size_t)l * 2 * 3072 * KDIM, Wub, 2 * 3072 * KDIM / 4);
    // xp = act * W_ih^T + b_ih
    dim3 gg(MDIM / 128, NDIM / 128);
    gemm_xp<<<gg, 256, 0, stream>>>(act, Wub, b_ih + l * NDIM, xp);
    // W_hh[l] -> bf16 into the same union buffer (W_ih copy no longer needed)
    f32_to_bf16_k<<<6144, 256, 0, stream>>>(
        W_hh + (size_t)l * 2 * 3072 * HID, Wub, 2 * 3072 * HID / 4);

    // persistent cooperative scan over all 256 steps
    const float* xp_c = xp;
    const unsigned short* Wbf_c = Wub;
    const float* bhl = b_hh + l * NDIM;
    const float* h0l = h0 + (size_t)l * 2 * BATCH * HID;
    float* hfA_ = hfA; float* hfB_ = hfB;
    unsigned short* hbA_ = hbA; unsigned short* hbB_ = hbB;
    unsigned short* dst_bf = (l == 2) ? nullptr : act;
    float* dst_f32 = (l == 2) ? out : nullptr;
    void* args[] = {
        (void*)&xp_c, (void*)&Wbf_c, (void*)&bhl, (void*)&h0l,
        (void*)&hfA_, (void*)&hfB_, (void*)&hbA_, (void*)&hbB_,
        (void*)&dst_bf, (void*)&dst_f32,
    };
    hipLaunchCooperativeKernel((void*)gru_scan, dim3(128), dim3(384),
                               args, 0, stream);
  }
}